// Round 20
// baseline (276.487 us; speedup 1.0000x reference)
//
#include <hip/hip_runtime.h>

#define NV   20000
#define MAXN 16

// ---------------------------------------------------------------------------
// Mask dtype detection (bool may arrive as int32 / byte / float32).
// ---------------------------------------------------------------------------
__global__ void detect_mask_kind(const unsigned int* __restrict__ m,
                                 int* __restrict__ flag) {
    if (threadIdx.x == 0 && blockIdx.x == 0) {
        int allint = 1, allflt = 1;
        #pragma unroll 8
        for (int k = 0; k < 64; ++k) {
            unsigned w = m[k];
            if (!(w == 0u || w == 1u)) allint = 0;
            if (!(w == 0u || w == 0x3F800000u)) allflt = 0;
        }
        *flag = allint ? 0 : (allflt ? 2 : 1);
    }
}

// ---------------------------------------------------------------------------
// One-time weight combine: per thread slot t=(c,i), 8 rows of 8
// (WQ, WK, W0, W1o0, W1o1, W2o0, W2o1, W2o2) = 16 float4 contiguous per t.
// ---------------------------------------------------------------------------
__global__ void compute_weights(const float* __restrict__ rr,
                                const float* __restrict__ vb0,
                                const float* __restrict__ vb1,
                                const float* __restrict__ vb2,
                                const float* __restrict__ qc,
                                const float* __restrict__ kc,
                                const float* __restrict__ w0p,
                                const float* __restrict__ w1p,
                                const float* __restrict__ w2p,
                                float4* __restrict__ wt) {
    const int t = threadIdx.x;
    const int c = t & 31;
    const int i = t >> 5;
    float WQr[8], WKr[8], W0r[8], W1r0[8], W1r1[8], W2r0[8], W2r1[8], W2r2[8];
    #pragma unroll
    for (int j = 0; j < 8; ++j) {
        WQr[j] = 0.f; WKr[j] = 0.f; W0r[j] = 0.f; W1r0[j] = 0.f;
        W1r1[j] = 0.f; W2r0[j] = 0.f; W2r1[j] = 0.f; W2r2[j] = 0.f;
    }
    #pragma unroll
    for (int b = 0; b < 8; ++b) {
        const float qcb = qc[c * 8 + b];
        const float kcb = kc[c * 8 + b];
        const float w0b = w0p[c * 8 + b];
        const float w1b = w1p[c * 8 + b];
        const float w2b = w2p[c * 8 + b];
        const float* rrb = rr  + b * 64  + i * 8;
        const float* z0  = vb0 + b * 64  + i * 8;
        const float* z1  = vb1 + b * 128 + i * 8;   // [b][o][i][j]
        const float* z2  = vb2 + b * 192 + i * 8;
        #pragma unroll
        for (int j = 0; j < 8; ++j) {
            const float r = rrb[j];
            WQr[j]  = fmaf(qcb, r, WQr[j]);
            WKr[j]  = fmaf(kcb, r, WKr[j]);
            W0r[j]  = fmaf(w0b, z0[j],       W0r[j]);
            W1r0[j] = fmaf(w1b, z1[j],       W1r0[j]);
            W1r1[j] = fmaf(w1b, z1[64 + j],  W1r1[j]);
            W2r0[j] = fmaf(w2b, z2[j],       W2r0[j]);
            W2r1[j] = fmaf(w2b, z2[64 + j],  W2r1[j]);
            W2r2[j] = fmaf(w2b, z2[128 + j], W2r2[j]);
        }
    }
    float4* o = wt + t * 16;
    o[ 0] = *(const float4*)&WQr[0];  o[ 1] = *(const float4*)&WQr[4];
    o[ 2] = *(const float4*)&WKr[0];  o[ 3] = *(const float4*)&WKr[4];
    o[ 4] = *(const float4*)&W0r[0];  o[ 5] = *(const float4*)&W0r[4];
    o[ 6] = *(const float4*)&W1r0[0]; o[ 7] = *(const float4*)&W1r0[4];
    o[ 8] = *(const float4*)&W1r1[0]; o[ 9] = *(const float4*)&W1r1[4];
    o[10] = *(const float4*)&W2r0[0]; o[11] = *(const float4*)&W2r0[4];
    o[12] = *(const float4*)&W2r1[0]; o[13] = *(const float4*)&W2r1[4];
    o[14] = *(const float4*)&W2r2[0]; o[15] = *(const float4*)&W2r2[4];
}

__device__ __forceinline__ float dot8a(const float* __restrict__ w,
                                       const float* __restrict__ f) {
    float s = w[0] * f[0];
    #pragma unroll
    for (int j = 1; j < 8; ++j) s = fmaf(w[j], f[j], s);
    return s;
}

__device__ __forceinline__ float dot8f4(const float4& a, const float4& b,
                                        const float* __restrict__ f) {
    return fmaf(a.x, f[0], fmaf(a.y, f[1], fmaf(a.z, f[2], fmaf(a.w, f[3],
           fmaf(b.x, f[4], fmaf(b.y, f[5], fmaf(b.z, f[6], b.w * f[7])))))));
}

// R19 (270.8us) with ONE change: launch_bounds (256,6) -> (256,5).
// R19's unified-regfile budget (512/6 ~ 85) sat exactly at the live set
// (40 VGPR + 48 AGPR-resident WV) -> ~3-dword/thread scratch spill
// (WRITE 79MB vs 20MB output). R16 established occupancy in this range is
// worth ~nothing (+10pts ~ -2us), while spill round-trips always cost:
// trade one wave of occupancy (65->54%) for a clean register allocation.
__global__ void __launch_bounds__(256, 5)
ge_attn_kernel(const float* __restrict__ x,
               const int*   __restrict__ neighbors,
               const void*  __restrict__ maskp,
               const float* __restrict__ ptm,
               const float* __restrict__ rpu,
               const float4* __restrict__ wt,
               const int*   __restrict__ mflag,
               float*       __restrict__ out) {
    const int t = threadIdx.x;
    const int c = t & 31;   // channel
    const int i = t >> 5;   // rep index (also the j-slot in aggregation)
    const int mf = *mflag;

    // f' store: [j][c][n], pad 18 (even): pair-b64 access 8B-aligned,
    // 2-way bank alias (free).  18.4KB
    __shared__ float fsh2[8][32][18];
    __shared__ float Fsh[8][32][6];   // aggregated features [j][c][k]  6KB
    __shared__ float sqni[16][8];     // Q[n,i] accumulators (pre-relu)
    __shared__ float kk[8];           // K[i]
    __shared__ float sn[16];          // final scaled score per neighbor
    __shared__ float smask[16];

    const int v  = blockIdx.x;
    const int vq = v * 16;

    // zero accumulators; mask -> LDS
    if (t < 128) ((float*)sqni)[t] = 0.f;
    else if (t < 144) sn[t - 128] = 0.f;
    if (t < 16) {
        int mm;
        if (mf == 0)      mm = (((const int*)maskp)[vq + t] != 0);
        else if (mf == 1) mm = (((const unsigned char*)maskp)[vq + t] != 0);
        else              mm = (((const float*)maskp)[vq + t] != 0.0f);
        smask[t] = mm ? 1.f : 0.f;
    }

    // WQ/WK rows (16 floats pinned)
    float WQK[16];
    {
        const float4* wp = wt + t * 16;
        #pragma unroll
        for (int r = 0; r < 4; ++r) {
            const float4 q = wp[r];
            WQK[r * 4 + 0] = q.x; WQK[r * 4 + 1] = q.y;
            WQK[r * 4 + 2] = q.z; WQK[r * 4 + 3] = q.w;
        }
        #pragma unroll
        for (int r = 0; r < 16; ++r)
            asm volatile("" : "+v"(WQK[r]));
    }

    // ---- phase 1: BOTH neighbors na=2i, nb=2i+1 together; b64 writes ----
    {
        const int na = 2 * i;
        int mma, mmb;
        if (mf == 0) {
            mma = (((const int*)maskp)[vq + na] != 0);
            mmb = (((const int*)maskp)[vq + na + 1] != 0);
        } else if (mf == 1) {
            mma = (((const unsigned char*)maskp)[vq + na] != 0);
            mmb = (((const unsigned char*)maskp)[vq + na + 1] != 0);
        } else {
            mma = (((const float*)maskp)[vq + na] != 0.0f);
            mmb = (((const float*)maskp)[vq + na + 1] != 0.0f);
        }
        const float ma = mma ? 1.f : 0.f;
        const float mb = mmb ? 1.f : 0.f;
        const int nbva = neighbors[vq + na];
        const int nbvb = neighbors[vq + na + 1];
        float xa[8], xb[8];
        {
            const float* pa = x + (size_t)nbva * 256 + c * 8;
            const float* pb = x + (size_t)nbvb * 256 + c * 8;
            *(float4*)&xa[0] = *(const float4*)pa;
            *(float4*)&xa[4] = *(const float4*)(pa + 4);
            *(float4*)&xb[0] = *(const float4*)pb;
            *(float4*)&xb[4] = *(const float4*)(pb + 4);
        }
        const float4* Pa = (const float4*)(ptm + (size_t)(vq + na) * 64);
        const float4* Pb = (const float4*)(ptm + (size_t)(vq + na + 1) * 64);
        #pragma unroll
        for (int j2 = 0; j2 < 4; ++j2) {
            float2 w0, w1;
            w0.x = dot8f4(Pa[4 * j2 + 0], Pa[4 * j2 + 1], xa) * ma;
            w1.x = dot8f4(Pa[4 * j2 + 2], Pa[4 * j2 + 3], xa) * ma;
            w0.y = dot8f4(Pb[4 * j2 + 0], Pb[4 * j2 + 1], xb) * mb;
            w1.y = dot8f4(Pb[4 * j2 + 2], Pb[4 * j2 + 3], xb) * mb;
            *(float2*)&fsh2[2 * j2    ][c][na] = w0;
            *(float2*)&fsh2[2 * j2 + 1][c][na] = w1;
        }
    }

    // K[i]: one shuffle reduction per vertex
    {
        float xc[8];
        const float* xv = x + (size_t)v * 256 + c * 8;
        *(float4*)&xc[0] = *(const float4*)xv;
        *(float4*)&xc[4] = *(const float4*)(xv + 4);
        float kp = dot8a(&WQK[8], xc);
        kp += __shfl_xor(kp, 1);
        kp += __shfl_xor(kp, 2);
        kp += __shfl_xor(kp, 4);
        kp += __shfl_xor(kp, 8);
        kp += __shfl_xor(kp, 16);
        if ((t & 31) == 0) kk[i] = kp;
    }

    __syncthreads();   // B1

    // ---- pass A: Q[n,i] partials, neighbor-pair b64 reads ----
    #pragma unroll 2
    for (int n2 = 0; n2 < 8; ++n2) {
        const int n = 2 * n2;
        float2 fp[8];
        #pragma unroll
        for (int j = 0; j < 8; ++j)
            fp[j] = *(const float2*)&fsh2[j][c][n];   // (fa[j], fb[j])
        float qa = fp[0].x * WQK[0];
        float qb = fp[0].y * WQK[0];
        #pragma unroll
        for (int j = 1; j < 8; ++j) {
            qa = fmaf(fp[j].x, WQK[j], qa);
            qb = fmaf(fp[j].y, WQK[j], qb);
        }
        qa += __shfl_xor(qa, 1);  qb += __shfl_xor(qb, 1);
        qa += __shfl_xor(qa, 2);  qb += __shfl_xor(qb, 2);
        qa += __shfl_xor(qa, 4);  qb += __shfl_xor(qb, 4);
        if ((c & 7) == 0) {
            atomicAdd(&sqni[n][i], qa);
            atomicAdd(&sqni[n + 1][i], qb);
        }
    }

    __syncthreads();   // B2: sqni done

    // fixup: sn[n] = 0.125*smask[n] * sum_i relu(Q[n,i]+K[i])  (scale folded)
    if (t < 128) {
        const int nn = t >> 3, ii = t & 7;
        atomicAdd(&sn[nn],
                  fmaxf(sqni[nn][ii] + kk[ii], 0.f) * (0.125f * smask[nn]));
    }

    __syncthreads();   // B3: sn done

    // ---- aggregation: thread (c, j=i) builds F0..F5[c,j] over neighbors ----
    float F0 = 0.f, F1 = 0.f, F2 = 0.f, F3 = 0.f, F4 = 0.f, F5 = 0.f;
    float ssum = 0.f;
    #pragma unroll 4
    for (int n2 = 0; n2 < 8; ++n2) {
        const int n = 2 * n2;
        const float sca = sn[n];
        const float scb = sn[n + 1];
        const float u0a = rpu[(size_t)(vq + n) * 2];
        const float u1a = rpu[(size_t)(vq + n) * 2 + 1];
        const float u0b = rpu[(size_t)(vq + n + 1) * 2];
        const float u1b = rpu[(size_t)(vq + n + 1) * 2 + 1];
        const float2 fpn = *(const float2*)&fsh2[i][c][n];   // (fa, fb)
        ssum += sca + scb;
        const float fsa = fpn.x * sca;
        const float fsb = fpn.y * scb;
        F0 += fsa + fsb;
        F1 = fmaf(u0a, fsa, fmaf(u0b, fsb, F1));
        F2 = fmaf(u1a, fsa, fmaf(u1b, fsb, F2));
        F3 = fmaf(u0a * u0a, fsa, fmaf(u0b * u0b, fsb, F3));
        F4 = fmaf(2.f * u0a * u1a, fsa, fmaf(2.f * u0b * u1b, fsb, F4));
        F5 = fmaf(u1a * u1a, fsa, fmaf(u1b * u1b, fsb, F5));
    }
    *(float2*)&Fsh[i][c][0] = make_float2(F0, F1);
    *(float2*)&Fsh[i][c][2] = make_float2(F2, F3);
    *(float2*)&Fsh[i][c][4] = make_float2(F4, F5);

    __syncthreads();   // B4: Fsh done

    // ---- final: load WV at the single use site (unpinned), contract ----
    float WV[48];
    {
        const float4* wp = wt + t * 16 + 4;
        #pragma unroll
        for (int r = 0; r < 12; ++r) {
            const float4 q = wp[r];
            WV[r * 4 + 0] = q.x; WV[r * 4 + 1] = q.y;
            WV[r * 4 + 2] = q.z; WV[r * 4 + 3] = q.w;
        }
    }
    float a0 = 0.f, a1 = 0.f, a2 = 0.f;
    #pragma unroll
    for (int jj = 0; jj < 8; ++jj) {
        const float2 F01 = *(const float2*)&Fsh[jj][c][0];
        const float2 F23 = *(const float2*)&Fsh[jj][c][2];
        const float2 F45 = *(const float2*)&Fsh[jj][c][4];
        a0 = fmaf(WV[     jj], F01.x, a0);
        a1 = fmaf(WV[ 8 + jj], F01.y, a1);
        a2 = fmaf(WV[16 + jj], F23.x, a2);
        a0 = fmaf(WV[24 + jj], F23.y, a0);
        a1 = fmaf(WV[32 + jj], F45.x, a1);
        a2 = fmaf(WV[40 + jj], F45.y, a2);
    }
    const float acc = a0 + a1 + a2;
    out[(size_t)v * 256 + c * 8 + i] = acc / fmaxf(ssum, 1e-8f);
}

extern "C" void kernel_launch(void* const* d_in, const int* in_sizes, int n_in,
                              void* d_out, int out_size, void* d_ws, size_t ws_size,
                              hipStream_t stream) {
    const float* x         = (const float*)d_in[0];
    const int*   neighbors = (const int*)d_in[1];
    const void*  maskp     = d_in[2];
    const float* ptm       = (const float*)d_in[3];
    const float* rpu       = (const float*)d_in[4];
    const float* rr        = (const float*)d_in[5];
    const float* vb0       = (const float*)d_in[6];
    const float* vb1       = (const float*)d_in[7];
    const float* vb2       = (const float*)d_in[8];
    const float* qc        = (const float*)d_in[9];
    const float* kc        = (const float*)d_in[10];
    const float* w0p       = (const float*)d_in[11];
    const float* w1p       = (const float*)d_in[12];
    const float* w2p       = (const float*)d_in[13];
    float* out = (float*)d_out;

    int*    flag = (int*)d_ws;
    float4* wtab = (float4*)((char*)d_ws + 1024);   // 64KB table

    detect_mask_kind<<<1, 64, 0, stream>>>((const unsigned int*)maskp, flag);
    compute_weights<<<1, 256, 0, stream>>>(rr, vb0, vb1, vb2,
                                           qc, kc, w0p, w1p, w2p, wtab);
    ge_attn_kernel<<<NV, 256, 0, stream>>>(x, neighbors, maskp, ptm, rpu,
                                           wtab, flag, out);
}

// Round 21
// 270.696 us; speedup vs baseline: 1.0214x; 1.0214x over previous
//
#include <hip/hip_runtime.h>

#define NV   20000
#define MAXN 16

// ---------------------------------------------------------------------------
// Mask dtype detection (bool may arrive as int32 / byte / float32).
// ---------------------------------------------------------------------------
__global__ void detect_mask_kind(const unsigned int* __restrict__ m,
                                 int* __restrict__ flag) {
    if (threadIdx.x == 0 && blockIdx.x == 0) {
        int allint = 1, allflt = 1;
        #pragma unroll 8
        for (int k = 0; k < 64; ++k) {
            unsigned w = m[k];
            if (!(w == 0u || w == 1u)) allint = 0;
            if (!(w == 0u || w == 0x3F800000u)) allflt = 0;
        }
        *flag = allint ? 0 : (allflt ? 2 : 1);
    }
}

// ---------------------------------------------------------------------------
// One-time weight combine: per thread slot t=(c,i), 8 rows of 8
// (WQ, WK, W0, W1o0, W1o1, W2o0, W2o1, W2o2) = 16 float4 contiguous per t.
// ---------------------------------------------------------------------------
__global__ void compute_weights(const float* __restrict__ rr,
                                const float* __restrict__ vb0,
                                const float* __restrict__ vb1,
                                const float* __restrict__ vb2,
                                const float* __restrict__ qc,
                                const float* __restrict__ kc,
                                const float* __restrict__ w0p,
                                const float* __restrict__ w1p,
                                const float* __restrict__ w2p,
                                float4* __restrict__ wt) {
    const int t = threadIdx.x;
    const int c = t & 31;
    const int i = t >> 5;
    float WQr[8], WKr[8], W0r[8], W1r0[8], W1r1[8], W2r0[8], W2r1[8], W2r2[8];
    #pragma unroll
    for (int j = 0; j < 8; ++j) {
        WQr[j] = 0.f; WKr[j] = 0.f; W0r[j] = 0.f; W1r0[j] = 0.f;
        W1r1[j] = 0.f; W2r0[j] = 0.f; W2r1[j] = 0.f; W2r2[j] = 0.f;
    }
    #pragma unroll
    for (int b = 0; b < 8; ++b) {
        const float qcb = qc[c * 8 + b];
        const float kcb = kc[c * 8 + b];
        const float w0b = w0p[c * 8 + b];
        const float w1b = w1p[c * 8 + b];
        const float w2b = w2p[c * 8 + b];
        const float* rrb = rr  + b * 64  + i * 8;
        const float* z0  = vb0 + b * 64  + i * 8;
        const float* z1  = vb1 + b * 128 + i * 8;   // [b][o][i][j]
        const float* z2  = vb2 + b * 192 + i * 8;
        #pragma unroll
        for (int j = 0; j < 8; ++j) {
            const float r = rrb[j];
            WQr[j]  = fmaf(qcb, r, WQr[j]);
            WKr[j]  = fmaf(kcb, r, WKr[j]);
            W0r[j]  = fmaf(w0b, z0[j],       W0r[j]);
            W1r0[j] = fmaf(w1b, z1[j],       W1r0[j]);
            W1r1[j] = fmaf(w1b, z1[64 + j],  W1r1[j]);
            W2r0[j] = fmaf(w2b, z2[j],       W2r0[j]);
            W2r1[j] = fmaf(w2b, z2[64 + j],  W2r1[j]);
            W2r2[j] = fmaf(w2b, z2[128 + j], W2r2[j]);
        }
    }
    float4* o = wt + t * 16;
    o[ 0] = *(const float4*)&WQr[0];  o[ 1] = *(const float4*)&WQr[4];
    o[ 2] = *(const float4*)&WKr[0];  o[ 3] = *(const float4*)&WKr[4];
    o[ 4] = *(const float4*)&W0r[0];  o[ 5] = *(const float4*)&W0r[4];
    o[ 6] = *(const float4*)&W1r0[0]; o[ 7] = *(const float4*)&W1r0[4];
    o[ 8] = *(const float4*)&W1r1[0]; o[ 9] = *(const float4*)&W1r1[4];
    o[10] = *(const float4*)&W2r0[0]; o[11] = *(const float4*)&W2r0[4];
    o[12] = *(const float4*)&W2r1[0]; o[13] = *(const float4*)&W2r1[4];
    o[14] = *(const float4*)&W2r2[0]; o[15] = *(const float4*)&W2r2[4];
}

__device__ __forceinline__ float dot8a(const float* __restrict__ w,
                                       const float* __restrict__ f) {
    float s = w[0] * f[0];
    #pragma unroll
    for (int j = 1; j < 8; ++j) s = fmaf(w[j], f[j], s);
    return s;
}

__device__ __forceinline__ float dot8f4(const float4& a, const float4& b,
                                        const float* __restrict__ f) {
    return fmaf(a.x, f[0], fmaf(a.y, f[1], fmaf(a.z, f[2], fmaf(a.w, f[3],
           fmaf(b.x, f[4], fmaf(b.y, f[5], fmaf(b.z, f[6], b.w * f[7])))))));
}

// R19 (270.8us, best) with the epilogue restructured so launch_bounds(256,6)
// holds WITHOUT the ~3-dword spill R19 paid (WRITE 79MB): the final
// contraction is separable by k-pair, so WV is loaded in THREE chunks of 16
// floats (acc = sum_kp sum_jj WVc[jj]*F_{2kp} + WVc[8+jj]*F_{2kp+1}),
// cutting peak epilogue liveness by ~32 regs. R20 established spill-free at
// 54% occ = 276us and R19 spilled at 65% occ = 271us; this aims for
// spill-free at 65%.
__global__ void __launch_bounds__(256, 6)
ge_attn_kernel(const float* __restrict__ x,
               const int*   __restrict__ neighbors,
               const void*  __restrict__ maskp,
               const float* __restrict__ ptm,
               const float* __restrict__ rpu,
               const float4* __restrict__ wt,
               const int*   __restrict__ mflag,
               float*       __restrict__ out) {
    const int t = threadIdx.x;
    const int c = t & 31;   // channel
    const int i = t >> 5;   // rep index (also the j-slot in aggregation)
    const int mf = *mflag;

    // f' store: [j][c][n], pad 18 (even): pair-b64 access 8B-aligned,
    // 2-way bank alias (free).  18.4KB
    __shared__ float fsh2[8][32][18];
    __shared__ float Fsh[8][32][6];   // aggregated features [j][c][k]  6KB
    __shared__ float sqni[16][8];     // Q[n,i] accumulators (pre-relu)
    __shared__ float kk[8];           // K[i]
    __shared__ float sn[16];          // final scaled score per neighbor
    __shared__ float smask[16];

    const int v  = blockIdx.x;
    const int vq = v * 16;

    // zero accumulators; mask -> LDS
    if (t < 128) ((float*)sqni)[t] = 0.f;
    else if (t < 144) sn[t - 128] = 0.f;
    if (t < 16) {
        int mm;
        if (mf == 0)      mm = (((const int*)maskp)[vq + t] != 0);
        else if (mf == 1) mm = (((const unsigned char*)maskp)[vq + t] != 0);
        else              mm = (((const float*)maskp)[vq + t] != 0.0f);
        smask[t] = mm ? 1.f : 0.f;
    }

    // WQ/WK rows (16 floats pinned)
    float WQK[16];
    {
        const float4* wp = wt + t * 16;
        #pragma unroll
        for (int r = 0; r < 4; ++r) {
            const float4 q = wp[r];
            WQK[r * 4 + 0] = q.x; WQK[r * 4 + 1] = q.y;
            WQK[r * 4 + 2] = q.z; WQK[r * 4 + 3] = q.w;
        }
        #pragma unroll
        for (int r = 0; r < 16; ++r)
            asm volatile("" : "+v"(WQK[r]));
    }

    // ---- phase 1: BOTH neighbors na=2i, nb=2i+1 together; b64 writes ----
    {
        const int na = 2 * i;
        int mma, mmb;
        if (mf == 0) {
            mma = (((const int*)maskp)[vq + na] != 0);
            mmb = (((const int*)maskp)[vq + na + 1] != 0);
        } else if (mf == 1) {
            mma = (((const unsigned char*)maskp)[vq + na] != 0);
            mmb = (((const unsigned char*)maskp)[vq + na + 1] != 0);
        } else {
            mma = (((const float*)maskp)[vq + na] != 0.0f);
            mmb = (((const float*)maskp)[vq + na + 1] != 0.0f);
        }
        const float ma = mma ? 1.f : 0.f;
        const float mb = mmb ? 1.f : 0.f;
        const int nbva = neighbors[vq + na];
        const int nbvb = neighbors[vq + na + 1];
        float xa[8], xb[8];
        {
            const float* pa = x + (size_t)nbva * 256 + c * 8;
            const float* pb = x + (size_t)nbvb * 256 + c * 8;
            *(float4*)&xa[0] = *(const float4*)pa;
            *(float4*)&xa[4] = *(const float4*)(pa + 4);
            *(float4*)&xb[0] = *(const float4*)pb;
            *(float4*)&xb[4] = *(const float4*)(pb + 4);
        }
        const float4* Pa = (const float4*)(ptm + (size_t)(vq + na) * 64);
        const float4* Pb = (const float4*)(ptm + (size_t)(vq + na + 1) * 64);
        #pragma unroll
        for (int j2 = 0; j2 < 4; ++j2) {
            float2 w0, w1;
            w0.x = dot8f4(Pa[4 * j2 + 0], Pa[4 * j2 + 1], xa) * ma;
            w1.x = dot8f4(Pa[4 * j2 + 2], Pa[4 * j2 + 3], xa) * ma;
            w0.y = dot8f4(Pb[4 * j2 + 0], Pb[4 * j2 + 1], xb) * mb;
            w1.y = dot8f4(Pb[4 * j2 + 2], Pb[4 * j2 + 3], xb) * mb;
            *(float2*)&fsh2[2 * j2    ][c][na] = w0;
            *(float2*)&fsh2[2 * j2 + 1][c][na] = w1;
        }
    }

    // K[i]: one shuffle reduction per vertex
    {
        float xc[8];
        const float* xv = x + (size_t)v * 256 + c * 8;
        *(float4*)&xc[0] = *(const float4*)xv;
        *(float4*)&xc[4] = *(const float4*)(xv + 4);
        float kp = dot8a(&WQK[8], xc);
        kp += __shfl_xor(kp, 1);
        kp += __shfl_xor(kp, 2);
        kp += __shfl_xor(kp, 4);
        kp += __shfl_xor(kp, 8);
        kp += __shfl_xor(kp, 16);
        if ((t & 31) == 0) kk[i] = kp;
    }

    __syncthreads();   // B1

    // ---- pass A: Q[n,i] partials, neighbor-pair b64 reads ----
    #pragma unroll 2
    for (int n2 = 0; n2 < 8; ++n2) {
        const int n = 2 * n2;
        float2 fp[8];
        #pragma unroll
        for (int j = 0; j < 8; ++j)
            fp[j] = *(const float2*)&fsh2[j][c][n];   // (fa[j], fb[j])
        float qa = fp[0].x * WQK[0];
        float qb = fp[0].y * WQK[0];
        #pragma unroll
        for (int j = 1; j < 8; ++j) {
            qa = fmaf(fp[j].x, WQK[j], qa);
            qb = fmaf(fp[j].y, WQK[j], qb);
        }
        qa += __shfl_xor(qa, 1);  qb += __shfl_xor(qb, 1);
        qa += __shfl_xor(qa, 2);  qb += __shfl_xor(qb, 2);
        qa += __shfl_xor(qa, 4);  qb += __shfl_xor(qb, 4);
        if ((c & 7) == 0) {
            atomicAdd(&sqni[n][i], qa);
            atomicAdd(&sqni[n + 1][i], qb);
        }
    }

    __syncthreads();   // B2: sqni done

    // fixup: sn[n] = 0.125*smask[n] * sum_i relu(Q[n,i]+K[i])  (scale folded)
    if (t < 128) {
        const int nn = t >> 3, ii = t & 7;
        atomicAdd(&sn[nn],
                  fmaxf(sqni[nn][ii] + kk[ii], 0.f) * (0.125f * smask[nn]));
    }

    __syncthreads();   // B3: sn done

    // ---- aggregation: thread (c, j=i) builds F0..F5[c,j] over neighbors ----
    float F0 = 0.f, F1 = 0.f, F2 = 0.f, F3 = 0.f, F4 = 0.f, F5 = 0.f;
    float ssum = 0.f;
    #pragma unroll 4
    for (int n2 = 0; n2 < 8; ++n2) {
        const int n = 2 * n2;
        const float sca = sn[n];
        const float scb = sn[n + 1];
        const float u0a = rpu[(size_t)(vq + n) * 2];
        const float u1a = rpu[(size_t)(vq + n) * 2 + 1];
        const float u0b = rpu[(size_t)(vq + n + 1) * 2];
        const float u1b = rpu[(size_t)(vq + n + 1) * 2 + 1];
        const float2 fpn = *(const float2*)&fsh2[i][c][n];   // (fa, fb)
        ssum += sca + scb;
        const float fsa = fpn.x * sca;
        const float fsb = fpn.y * scb;
        F0 += fsa + fsb;
        F1 = fmaf(u0a, fsa, fmaf(u0b, fsb, F1));
        F2 = fmaf(u1a, fsa, fmaf(u1b, fsb, F2));
        F3 = fmaf(u0a * u0a, fsa, fmaf(u0b * u0b, fsb, F3));
        F4 = fmaf(2.f * u0a * u1a, fsa, fmaf(2.f * u0b * u1b, fsb, F4));
        F5 = fmaf(u1a * u1a, fsa, fmaf(u1b * u1b, fsb, F5));
    }
    *(float2*)&Fsh[i][c][0] = make_float2(F0, F1);
    *(float2*)&Fsh[i][c][2] = make_float2(F2, F3);
    *(float2*)&Fsh[i][c][4] = make_float2(F4, F5);

    __syncthreads();   // B4: Fsh done

    // ---- final: chunked contraction, 16 WV floats live per k-pair ----
    float acc = 0.f;
    {
        const float4* wp = wt + t * 16 + 4;
        #pragma unroll
        for (int kp = 0; kp < 3; ++kp) {
            float WVc[16];
            #pragma unroll
            for (int r = 0; r < 4; ++r) {
                const float4 q = wp[kp * 4 + r];
                WVc[r * 4 + 0] = q.x; WVc[r * 4 + 1] = q.y;
                WVc[r * 4 + 2] = q.z; WVc[r * 4 + 3] = q.w;
            }
            float aa = 0.f, ab = 0.f;
            #pragma unroll
            for (int jj = 0; jj < 8; ++jj) {
                const float2 Fp = *(const float2*)&Fsh[jj][c][2 * kp];
                aa = fmaf(WVc[jj],     Fp.x, aa);
                ab = fmaf(WVc[8 + jj], Fp.y, ab);
            }
            acc += aa + ab;
        }
    }
    out[(size_t)v * 256 + c * 8 + i] = acc / fmaxf(ssum, 1e-8f);
}

extern "C" void kernel_launch(void* const* d_in, const int* in_sizes, int n_in,
                              void* d_out, int out_size, void* d_ws, size_t ws_size,
                              hipStream_t stream) {
    const float* x         = (const float*)d_in[0];
    const int*   neighbors = (const int*)d_in[1];
    const void*  maskp     = d_in[2];
    const float* ptm       = (const float*)d_in[3];
    const float* rpu       = (const float*)d_in[4];
    const float* rr        = (const float*)d_in[5];
    const float* vb0       = (const float*)d_in[6];
    const float* vb1       = (const float*)d_in[7];
    const float* vb2       = (const float*)d_in[8];
    const float* qc        = (const float*)d_in[9];
    const float* kc        = (const float*)d_in[10];
    const float* w0p       = (const float*)d_in[11];
    const float* w1p       = (const float*)d_in[12];
    const float* w2p       = (const float*)d_in[13];
    float* out = (float*)d_out;

    int*    flag = (int*)d_ws;
    float4* wtab = (float4*)((char*)d_ws + 1024);   // 64KB table

    detect_mask_kind<<<1, 64, 0, stream>>>((const unsigned int*)maskp, flag);
    compute_weights<<<1, 256, 0, stream>>>(rr, vb0, vb1, vb2,
                                           qc, kc, w0p, w1p, w2p, wtab);
    ge_attn_kernel<<<NV, 256, 0, stream>>>(x, neighbors, maskp, ptm, rpu,
                                           wtab, flag, out);
}